// Round 5
// baseline (815.422 us; speedup 1.0000x reference)
//
#include <hip/hip_runtime.h>
#include <math.h>

#define P    13
#define PP   169
#define NIMG 4
#define HIMG 256
#define HP   280            // 256 + 2*12
#define HO   268            // 280 - 13 + 1

typedef __attribute__((ext_vector_type(8))) short short8_t;
typedef __attribute__((ext_vector_type(4))) float f32x4;

__device__ __forceinline__ ushort f2bf(float x) {
    union { float f; unsigned u; } a; a.f = x;
    unsigned r = a.u + 0x7fffu + ((a.u >> 16) & 1u);   // RNE
    return (ushort)(r >> 16);
}
__device__ __forceinline__ float bf2f(ushort b) {
    union { float f; unsigned u; } a; a.u = ((unsigned)b) << 16;
    return a.f;
}

// ---------------- prep1: Pm1 -> MFMA frag layout (plain K), split bf16 hi/lo ----------------
__global__ __launch_bounds__(256) void prep1_kernel(const float* __restrict__ Pm1,
                                                    ushort* __restrict__ prep1) {
    int idx = blockIdx.x*256 + threadIdx.x;
    if (idx >= 6*11*512) return;
    int j    = idx & 7;
    int lane = (idx >> 3) & 63;
    int rest = idx >> 9;
    int mt   = rest % 11;
    int ks   = rest / 11;
    int row  = mt*16 + (lane & 15);
    int k    = ks*32 + 8*(lane>>4) + j;
    float val = (row < PP && k < PP) ? Pm1[row*PP + k] : 0.0f;
    ushort h = f2bf(val);
    ushort lo = f2bf(val - bf2f(h));
    prep1[((ks*2+0)*11 + mt)*512 + lane*8 + j] = h;
    prep1[((ks*2+1)*11 + mt)*512 + lane*8 + j] = lo;
}

// ---------------- invert: register-blocked Gauss-Jordan (verified R4) ----------------
// Single-block kernel: occupancy irrelevant -> max VGPR cap, zero spill.
__global__ __launch_bounds__(512, 1) void invert_kernel(const float* __restrict__ Pm1,
                                                        ushort* __restrict__ prep2) {
    extern __shared__ float sm[];
    float* Adump = sm;                      // 169*192
    float* dcolB = sm + 169*192;            // 2*192
    float* prowB = dcolB + 384;             // 2*192
    float* krowB = prowB + 384;             // 2*192
    int*   perm  = (int*)(krowB + 384);     // 169

    int tid = threadIdx.x;
    int ti = tid >> 4, tj = tid & 15;
    int l64 = tid & 63;
    int row0 = 6*ti;

    float a[6][12];
#pragma unroll
    for (int m = 0; m < 6; ++m)
#pragma unroll
      for (int u = 0; u < 12; ++u) {
        int i = row0 + m, kc = 11*tj + u;
        a[m][u] = (i < PP && u < 11 && kc < PP) ? Pm1[i*PP + kc] : 0.0f;
      }
    __syncthreads();

    for (int k = 0; k < PP; ++k) {
        int par = k & 1;
        float* dcol = dcolB + par*192;
        float* prow = prowB + par*192;
        float* krow = krowB + par*192;
        int gk = (k*5958) >> 16;           // k/11
        int uk = k - 11*gk;
        if (tj == gk) {
#pragma unroll
            for (int u = 0; u < 12; ++u) if (u == uk) {
#pragma unroll
                for (int m = 0; m < 6; ++m) dcol[row0 + m] = a[m][u];
            }
        }
        __syncthreads();   // barrier A
        unsigned key = 0; float val = 0.0f;
        for (int i = k + l64; i < PP; i += 64) {
            float v = dcol[i];
            unsigned bits = __float_as_uint(fabsf(v));
            unsigned kk2 = (bits & 0xFFFFFF00u) | (unsigned)(255 - i);
            if (kk2 > key) { key = kk2; val = v; }
        }
#pragma unroll
        for (int m2 = 1; m2 < 64; m2 <<= 1) {
            unsigned ok = __shfl_xor(key, m2);
            float    ov = __shfl_xor(val, m2);
            if (ok > key) { key = ok; val = ov; }
        }
        int p = 255 - (int)(key & 0xFFu);
        float pv = val;
        int tip = (p*10923) >> 16;  int mp = p - 6*tip;   // p/6
        int tik = (k*10923) >> 16;  int mk = k - 6*tik;   // k/6
        if (ti == tip) {
#pragma unroll
            for (int m = 0; m < 6; ++m) if (m == mp) {
#pragma unroll
                for (int u4 = 0; u4 < 3; ++u4) {
                    float4 v4; v4.x=a[m][4*u4]; v4.y=a[m][4*u4+1]; v4.z=a[m][4*u4+2]; v4.w=a[m][4*u4+3];
                    *reinterpret_cast<float4*>(&prow[12*tj + 4*u4]) = v4;
                }
            }
        }
        if (ti == tik) {
#pragma unroll
            for (int m = 0; m < 6; ++m) if (m == mk) {
#pragma unroll
                for (int u4 = 0; u4 < 3; ++u4) {
                    float4 v4; v4.x=a[m][4*u4]; v4.y=a[m][4*u4+1]; v4.z=a[m][4*u4+2]; v4.w=a[m][4*u4+3];
                    *reinterpret_cast<float4*>(&krow[12*tj + 4*u4]) = v4;
                }
            }
        }
        if (tid == 0) perm[k] = p;
        __syncthreads();   // barrier B
        float invpv = 1.0f / pv;
        float s[12];
        {
            float4 p0 = *reinterpret_cast<float4*>(&prow[12*tj]);
            float4 p1 = *reinterpret_cast<float4*>(&prow[12*tj + 4]);
            float4 p2 = *reinterpret_cast<float4*>(&prow[12*tj + 8]);
            s[0]=p0.x*invpv; s[1]=p0.y*invpv; s[2]=p0.z*invpv; s[3]=p0.w*invpv;
            s[4]=p1.x*invpv; s[5]=p1.y*invpv; s[6]=p1.z*invpv; s[7]=p1.w*invpv;
            s[8]=p2.x*invpv; s[9]=p2.y*invpv; s[10]=p2.z*invpv; s[11]=p2.w*invpv;
        }
        bool myg = (tj == gk);
        if (myg) {
#pragma unroll
            for (int u = 0; u < 12; ++u) if (u == uk) {
                s[u] = invpv;
#pragma unroll
                for (int m = 0; m < 6; ++m) a[m][u] = 0.0f;
            }
        }
        float d[6];
#pragma unroll
        for (int m = 0; m < 6; ++m) d[m] = dcol[row0 + m];
#pragma unroll
        for (int m = 0; m < 6; ++m)
#pragma unroll
          for (int u = 0; u < 12; ++u)
            a[m][u] = __builtin_fmaf(-d[m], s[u], a[m][u]);
        if (ti == tik) {
#pragma unroll
            for (int m = 0; m < 6; ++m) if (m == mk) {
#pragma unroll
                for (int u = 0; u < 12; ++u) a[m][u] = s[u];
            }
        }
        if (p != k && ti == tip) {
            float dk = dcol[k];
            float kr[12];
            float4 k0 = *reinterpret_cast<float4*>(&krow[12*tj]);
            float4 k1 = *reinterpret_cast<float4*>(&krow[12*tj + 4]);
            float4 k2 = *reinterpret_cast<float4*>(&krow[12*tj + 8]);
            kr[0]=k0.x; kr[1]=k0.y; kr[2]=k0.z; kr[3]=k0.w;
            kr[4]=k1.x; kr[5]=k1.y; kr[6]=k1.z; kr[7]=k1.w;
            kr[8]=k2.x; kr[9]=k2.y; kr[10]=k2.z; kr[11]=k2.w;
            if (myg) {
#pragma unroll
                for (int u = 0; u < 12; ++u) if (u == uk) kr[u] = 0.0f;
            }
#pragma unroll
            for (int m = 0; m < 6; ++m) if (m == mp) {
#pragma unroll
                for (int u = 0; u < 12; ++u) a[m][u] = __builtin_fmaf(-dk, s[u], kr[u]);
            }
        }
    }
    __syncthreads();
#pragma unroll
    for (int m = 0; m < 6; ++m) {
        int i = row0 + m;
        if (i < PP) {
#pragma unroll
            for (int u4 = 0; u4 < 3; ++u4) {
                float4 v; v.x = a[m][4*u4]; v.y = a[m][4*u4+1]; v.z = a[m][4*u4+2]; v.w = a[m][4*u4+3];
                *reinterpret_cast<float4*>(&Adump[i*192 + 12*tj + 4*u4]) = v;
            }
        }
    }
    __syncthreads();
    if (tid < PP) {
        for (int k = PP - 1; k >= 0; --k) {
            int p = perm[k];
            if (p != k) {
                int gk2 = (k*5958)>>16, gp2 = (p*5958)>>16;
                int c1 = gk2*12 + (k - 11*gk2);
                int c2 = gp2*12 + (p - 11*gp2);
                float t1 = Adump[tid*192 + c1];
                Adump[tid*192 + c1] = Adump[tid*192 + c2];
                Adump[tid*192 + c2] = t1;
            }
        }
    }
    __syncthreads();
    for (int o = tid; o < 6*2*11*512; o += 512) {
        int li = o & 511;
        int rest = o >> 9;
        int mt = rest % 11;
        int kp = rest / 11;
        int plane = kp & 1, ks = kp >> 1;
        int lane = li >> 3, j = li & 7;
        int row = mt*16 + (lane & 15);
        int kk = ks*32 + 8*(lane>>4) + j;
        float val = 0.0f;
        if (row < PP && kk < PP) {
            int g = (kk*5958) >> 16;
            val = Adump[row*192 + g*12 + (kk - 11*g)];
        }
        ushort h = f2bf(val);
        prep2[o] = plane ? f2bf(val - bf2f(h)) : h;
    }
}

// ---------------- fused: xr stage -> B-planes -> GEMM1 -> threshold -> GEMM2 -> fold ----------------
__device__ __forceinline__ f32x4 mfma3(short8_t ah, short8_t al, short8_t bh, short8_t bl, f32x4 acc) {
    acc = __builtin_amdgcn_mfma_f32_16x16x32_bf16(ah, bh, acc, 0, 0, 0);
    acc = __builtin_amdgcn_mfma_f32_16x16x32_bf16(al, bh, acc, 0, 0, 0);
    acc = __builtin_amdgcn_mfma_f32_16x16x32_bf16(ah, bl, acc, 0, 0, 0);
    return acc;
}

// LDS layout: planes (2x24x64 short8 = 49152 B) | xr 448f | fp 448f | cnt 64i
__global__ __launch_bounds__(512, 2) void fused_kernel(
    const float* __restrict__ x,
    const ushort* __restrict__ prep1,
    const ushort* __restrict__ prep2,
    const float* __restrict__ sigma_,
    float* __restrict__ wmap,
    float* __restrict__ num)
{
    extern __shared__ char smem[];
    ushort* planes = (ushort*)smem;                 // [(plane*24+ksf)*64 + lane]*8 + j
    float*  xr  = (float*)(smem + 49152);           // 448 floats [16][28]
    float*  fp  = (float*)(smem + 49152 + 1792);    // 448 floats
    int*    cnt = (int*)(smem + 49152 + 3584);      // 64 ints

    int tid = threadIdx.x;
    int w = tid >> 6, l = tid & 63;
    int q = l >> 4, c = l & 15;
    int mg = w >> 1, ng = w & 1;
    int ntiles = (mg == 3) ? 2 : 3;
    int n = blockIdx.z, ho0 = blockIdx.y * 4, wo0 = blockIdx.x * 16;
    float lam = 6.0f * sigma_[0];
    const float* xn = x + n*HIMG*HIMG;

    // ---- stage xr (reflect-pad + affine fused), init fp/cnt ----
    if (tid < 448) {
        int idx = tid;
        int i = (idx*586) >> 14;                    // idx/28
        int j = idx - i*28;
        int gi = ho0 + i - 12;
        gi = (gi < 0) ? -gi : gi; gi = (gi > HIMG-1) ? (2*(HIMG-1) - gi) : gi;
        int gj = wo0 + j - 12;
        gj = (gj < 0) ? -gj : gj; gj = (gj > HIMG-1) ? (2*(HIMG-1) - gj) : gj;
        xr[idx] = 2.0f * xn[gi*HIMG + gj] - 1.0f;
        fp[idx] = 0.0f;
    }
    if (tid < 64) cnt[tid] = 0;
    __syncthreads();   // b0: xr ready

    // ---- build B-planes (3 frags per wave) ----
#pragma unroll
    for (int b = 0; b < 3; ++b) {
        int ksf = w*3 + b;
        int ks = ksf >> 2, cfp = ksf & 3;
        short8_t bh, bl;
#pragma unroll
        for (int j = 0; j < 8; ++j) {
            int k = ks*32 + 8*q + j;
            float v = 0.0f;
            if (k < PP) {
                int di = (k*5042) >> 16;            // k/13
                int dj = k - 13*di;
                v = xr[(cfp + di)*28 + c + dj];
            }
            ushort h = f2bf(v);
            bh[j] = (short)h;
            bl[j] = (short)f2bf(v - bf2f(h));
        }
        *reinterpret_cast<short8_t*>(&planes[(( 0 + ksf)*64 + l)*8]) = bh;
        *reinterpret_cast<short8_t*>(&planes[((24 + ksf)*64 + l)*8]) = bl;
    }

    const short8_t* p1v = reinterpret_cast<const short8_t*>(prep1);
    const short8_t* p2v = reinterpret_cast<const short8_t*>(prep2);

    short8_t ahc[3], alc[3];
#pragma unroll
    for (int tt = 0; tt < 3; ++tt) if (tt < ntiles) {
        int mt = mg + 4*tt;
        ahc[tt] = p1v[(0*11 + mt)*64 + l];
        alc[tt] = p1v[(1*11 + mt)*64 + l];
    }

    f32x4 acc[3][2];
#pragma unroll
    for (int tt = 0; tt < 3; ++tt)
#pragma unroll
      for (int cf = 0; cf < 2; ++cf) acc[tt][cf] = (f32x4){0.f,0.f,0.f,0.f};

    __syncthreads();   // b1: B-planes ready

    // ---- GEMM1 (A streamed, 1-deep prefetch; B via direct short8 reads) ----
#pragma unroll 1
    for (int ks = 0; ks < 6; ++ks) {
        short8_t ahn[3], aln[3];
        if (ks < 5) {
#pragma unroll
            for (int tt = 0; tt < 3; ++tt) if (tt < ntiles) {
                int mt = mg + 4*tt;
                ahn[tt] = p1v[((2*(ks+1)+0)*11 + mt)*64 + l];
                aln[tt] = p1v[((2*(ks+1)+1)*11 + mt)*64 + l];
            }
        }
#pragma unroll
        for (int cf = 0; cf < 2; ++cf) {
            int ksf = ks*4 + 2*ng + cf;
            short8_t bh = *reinterpret_cast<const short8_t*>(&planes[(( 0 + ksf)*64 + l)*8]);
            short8_t bl = *reinterpret_cast<const short8_t*>(&planes[((24 + ksf)*64 + l)*8]);
#pragma unroll
            for (int tt = 0; tt < 3; ++tt) if (tt < ntiles)
                acc[tt][cf] = mfma3(ahc[tt], alc[tt], bh, bl, acc[tt][cf]);
        }
        if (ks < 5) {
#pragma unroll
            for (int tt = 0; tt < 3; ++tt) if (tt < ntiles) { ahc[tt] = ahn[tt]; alc[tt] = aln[tt]; }
        }
    }
    __syncthreads();   // b2: B reads done; planes reusable for t

    // ---- threshold, pack t into planes, count ----
    int cadd[2] = {0, 0};
#pragma unroll
    for (int tt = 0; tt < 3; ++tt) if (tt < ntiles) {
        int mt = mg + 4*tt;
#pragma unroll
        for (int cf = 0; cf < 2; ++cf) {
            ushort th[4], tl[4];
#pragma unroll
            for (int e = 0; e < 4; ++e) {
                int r = mt*16 + 4*q + e;
                float dd = acc[tt][cf][e] / lam;
                bool keep = fabsf(dd) > 1.0f;
                float tv = keep ? dd*lam : 0.0f;
                cadd[cf] += (keep && r > 0 && r < PP) ? 1 : 0;
                th[e] = f2bf(tv);
                tl[e] = f2bf(tv - bf2f(th[e]));
            }
            if (mt < 11) {
                int r0 = mt*16 + 4*q;
                int ksf2 = (r0 >> 5)*4 + 2*ng + cf;
                int lane2 = ((r0 >> 3) & 3)*16 + c;
                int j0 = r0 & 7;                    // 0 or 4
                uint2 vh; vh.x = (uint)th[0] | ((uint)th[1] << 16); vh.y = (uint)th[2] | ((uint)th[3] << 16);
                uint2 vl; vl.x = (uint)tl[0] | ((uint)tl[1] << 16); vl.y = (uint)tl[2] | ((uint)tl[3] << 16);
                *reinterpret_cast<uint2*>(&planes[(( 0 + ksf2)*64 + lane2)*8 + j0]) = vh;
                *reinterpret_cast<uint2*>(&planes[((24 + ksf2)*64 + lane2)*8 + j0]) = vl;
            }
        }
    }
#pragma unroll
    for (int cf = 0; cf < 2; ++cf) {
        int v = cadd[cf];
        v += __shfl_xor(v, 16);
        v += __shfl_xor(v, 32);
        if (q == 0) atomicAdd(&cnt[32*ng + 16*cf + c], v);
    }

    // preload GEMM2 ks=0 A-frags
#pragma unroll
    for (int tt = 0; tt < 3; ++tt) if (tt < ntiles) {
        int mt = mg + 4*tt;
        ahc[tt] = p2v[(0*11 + mt)*64 + l];
        alc[tt] = p2v[(1*11 + mt)*64 + l];
    }
    __syncthreads();   // b3: t + cnt final

    float wgt[2];
#pragma unroll
    for (int cf = 0; cf < 2; ++cf) {
        int col = 32*ng + 16*cf + c;
        int cv = cnt[col];
        wgt[cf] = (wo0 + c < HO) ? 1.0f/(1.0f + (float)cv) : 0.0f;
        if (mg == 0 && q == 0 && wo0 + c < HO)
            wmap[(n*HO + ho0 + 2*ng + cf)*HO + wo0 + c] = wgt[cf];
    }

#pragma unroll
    for (int tt = 0; tt < 3; ++tt)
#pragma unroll
      for (int cf = 0; cf < 2; ++cf) acc[tt][cf] = (f32x4){0.f,0.f,0.f,0.f};

    // ---- GEMM2 (A streamed) ----
#pragma unroll 1
    for (int ks = 0; ks < 6; ++ks) {
        short8_t ahn[3], aln[3];
        if (ks < 5) {
#pragma unroll
            for (int tt = 0; tt < 3; ++tt) if (tt < ntiles) {
                int mt = mg + 4*tt;
                ahn[tt] = p2v[((2*(ks+1)+0)*11 + mt)*64 + l];
                aln[tt] = p2v[((2*(ks+1)+1)*11 + mt)*64 + l];
            }
        }
#pragma unroll
        for (int cf = 0; cf < 2; ++cf) {
            int ksf = ks*4 + 2*ng + cf;
            short8_t bh = *reinterpret_cast<const short8_t*>(&planes[(( 0 + ksf)*64 + l)*8]);
            short8_t bl = *reinterpret_cast<const short8_t*>(&planes[((24 + ksf)*64 + l)*8]);
#pragma unroll
            for (int tt = 0; tt < 3; ++tt) if (tt < ntiles)
                acc[tt][cf] = mfma3(ahc[tt], alc[tt], bh, bl, acc[tt][cf]);
        }
        if (ks < 5) {
#pragma unroll
            for (int tt = 0; tt < 3; ++tt) if (tt < ntiles) { ahc[tt] = ahn[tt]; alc[tt] = aln[tt]; }
        }
    }

    // ---- scale by w, fold into footprint ----
#pragma unroll
    for (int tt = 0; tt < 3; ++tt) if (tt < ntiles) {
        int mt = mg + 4*tt;
#pragma unroll
        for (int cf = 0; cf < 2; ++cf) {
#pragma unroll
            for (int e = 0; e < 4; ++e) {
                int r = mt*16 + 4*q + e;
                if (r < PP) {
                    int di = (r*5042) >> 16;        // r/13
                    int dj = r - 13*di;
                    atomicAdd(&fp[(2*ng + cf + di)*28 + c + dj], acc[tt][cf][e] * wgt[cf]);
                }
            }
        }
    }
    __syncthreads();   // b4

    float* nump = num + n*HP*HP;
    if (tid < 448) {
        int idx = tid;
        int i = (idx*586) >> 14;
        int j = idx - i*28;
        int gj = wo0 + j;
        if (gj < HP) atomicAdd(&nump[(ho0 + i)*HP + gj], fp[idx]);
    }
}

// ---------------- final: out = (num / box13(w) + 1)/2 (verified) ----------------
__global__ __launch_bounds__(256) void final_kernel(const float* __restrict__ num,
                                                    const float* __restrict__ wmap,
                                                    float* __restrict__ out)
{
    __shared__ float wr[28][28];
    int tid = threadIdx.x;
    int n = blockIdx.z;
    int y0 = blockIdx.y * 16, x0 = blockIdx.x * 16;
    const float* wp = wmap + n*HO*HO;
    for (int idx = tid; idx < 28*28; idx += 256) {
        int i = idx / 28, j = idx - (idx/28)*28;
        wr[i][j] = wp[(y0 + i)*HO + (x0 + j)];
    }
    __syncthreads();
    int py = tid >> 4, px = tid & 15;
    float dv = 0.0f;
#pragma unroll
    for (int a = 0; a < 13; ++a)
#pragma unroll
        for (int b = 0; b < 13; ++b)
            dv += wr[py + a][px + b];
    int y = y0 + py, x = x0 + px;
    float nv = num[(n*HP + (y + 12))*HP + (x + 12)];
    out[(n*HIMG + y)*HIMG + x] = (nv / dv + 1.0f) * 0.5f;
}

extern "C" void kernel_launch(void* const* d_in, const int* in_sizes, int n_in,
                              void* d_out, int out_size, void* d_ws, size_t ws_size,
                              hipStream_t stream) {
    const float* x      = (const float*)d_in[0];
    const float* sigma_ = (const float*)d_in[1];
    const float* Pm1    = (const float*)d_in[2];
    float* ws    = (float*)d_ws;
    float* wmap  = ws;                           // 287296 f
    float* num   = ws + 287296;                  // 313600 f
    ushort* prep1 = (ushort*)(ws + 600896);      // 67584 ushorts
    ushort* prep2 = (ushort*)(ws + 634688);      // 67584 ushorts
    float* out   = (float*)d_out;

    const int INV_LDS   = (169*192 + 3*384)*4 + 169*4;          // 135076
    const int FUSED_LDS = 49152 + 1792 + 1792 + 256;            // 52992
    hipFuncSetAttribute((const void*)invert_kernel, hipFuncAttributeMaxDynamicSharedMemorySize, INV_LDS);
    hipFuncSetAttribute((const void*)fused_kernel,  hipFuncAttributeMaxDynamicSharedMemorySize, FUSED_LDS);

    hipMemsetAsync(num, 0, (size_t)NIMG*HP*HP*sizeof(float), stream);
    prep1_kernel<<<(6*11*512 + 255)/256, 256, 0, stream>>>(Pm1, prep1);
    invert_kernel<<<1, 512, INV_LDS, stream>>>(Pm1, prep2);
    dim3 grid((HO + 15)/16, (HO + 3)/4, NIMG);   // 17 x 67 x 4
    fused_kernel<<<grid, 512, FUSED_LDS, stream>>>(x, prep1, prep2, sigma_, wmap, num);
    dim3 gridD(HIMG/16, HIMG/16, NIMG);
    final_kernel<<<gridD, 256, 0, stream>>>(num, wmap, out);
}

// Round 6
// 784.253 us; speedup vs baseline: 1.0397x; 1.0397x over previous
//
#include <hip/hip_runtime.h>
#include <math.h>

#define P    13
#define PP   169
#define NIMG 4
#define HIMG 256
#define HP   280            // 256 + 2*12
#define HO   268            // 280 - 13 + 1

typedef __attribute__((ext_vector_type(8))) short short8_t;
typedef __attribute__((ext_vector_type(4))) float f32x4;

__device__ __forceinline__ ushort f2bf(float x) {
    union { float f; unsigned u; } a; a.f = x;
    unsigned r = a.u + 0x7fffu + ((a.u >> 16) & 1u);   // RNE
    return (ushort)(r >> 16);
}
__device__ __forceinline__ float bf2f(ushort b) {
    union { float f; unsigned u; } a; a.u = ((unsigned)b) << 16;
    return a.f;
}

// ---------------- prep1: Pm1 -> MFMA frag layout (plain K), split bf16 hi/lo (verified) ----------------
__global__ __launch_bounds__(256) void prep1_kernel(const float* __restrict__ Pm1,
                                                    ushort* __restrict__ prep1) {
    int idx = blockIdx.x*256 + threadIdx.x;
    if (idx >= 6*11*512) return;
    int j    = idx & 7;
    int lane = (idx >> 3) & 63;
    int rest = idx >> 9;
    int mt   = rest % 11;
    int ks   = rest / 11;
    int row  = mt*16 + (lane & 15);
    int k    = ks*32 + 8*(lane>>4) + j;
    float val = (row < PP && k < PP) ? Pm1[row*PP + k] : 0.0f;
    ushort h = f2bf(val);
    ushort lo = f2bf(val - bf2f(h));
    prep1[((ks*2+0)*11 + mt)*512 + lane*8 + j] = h;
    prep1[((ks*2+1)*11 + mt)*512 + lane*8 + j] = lo;
}

// ---------------- invert: flipped-layout Gauss-Jordan, ONE barrier/iteration ----------------
// 512 threads: ti = tid>>4 owns cols c = ti*6+u (u<6); tj = tid&15 owns rows r = tj*11+m (m<11).
// Wave spans all tj -> pivot-row / row-k gathers are intra-wave shuffles. Only the pivot
// column crosses waves (LDS, double-buffered). Pivot search for k+1 runs in-register on the
// owner wave right after it updates its column, published through the same single barrier.
__global__ __launch_bounds__(512, 1) void invert_kernel(const float* __restrict__ Pm1,
                                                        ushort* __restrict__ prep2) {
    __shared__ float dcolB[2][176];
    __shared__ float pvbuf[2];
    __shared__ int   pbuf[2];
    __shared__ int   perm[PP];

    int tid = threadIdx.x;
    int ti = tid >> 4, tj = tid & 15;
    int l  = tid & 63;

    float a[11][6];
#pragma unroll
    for (int m = 0; m < 11; ++m)
#pragma unroll
      for (int u = 0; u < 6; ++u) {
        int r = tj*11 + m, c = ti*6 + u;
        a[m][u] = (r < PP && c < PP) ? Pm1[r*PP + c] : 0.0f;
      }

    // bootstrap: publish col 0 + pivot 0 into buffer 0
    {
        int tin = 0, un = 0;
        if (ti == tin) {
            float v[11];
#pragma unroll
            for (int uu = 0; uu < 6; ++uu) if (uu == un) {
#pragma unroll
                for (int m = 0; m < 11; ++m) v[m] = a[m][uu];
            }
#pragma unroll
            for (int m = 0; m < 11; ++m) dcolB[0][tj*11 + m] = v[m];
            unsigned key = 0; float val = 0.0f;
#pragma unroll
            for (int m = 0; m < 11; ++m) {
                int r = tj*11 + m;
                if (r < PP) {
                    unsigned bits = __float_as_uint(fabsf(v[m]));
                    unsigned kk2 = (bits & 0xFFFFFF00u) | (unsigned)(255 - r);
                    if (kk2 > key) { key = kk2; val = v[m]; }
                }
            }
#pragma unroll
            for (int mm = 1; mm < 16; mm <<= 1) {
                unsigned ok = __shfl_xor(key, mm);
                float    ov = __shfl_xor(val, mm);
                if (ok > key) { key = ok; val = ov; }
            }
            if (tj == 0) { pbuf[0] = 255 - (int)(key & 0xFFu); pvbuf[0] = val; }
        }
    }
    __syncthreads();

    for (int k = 0; k < PP; ++k) {
        int par = k & 1, npar = par ^ 1;
        int p = pbuf[par];
        float pv = pvbuf[par];
        float invpv = 1.0f / pv;
        int tj_p = (p*5958) >> 16;  int mp = p - 11*tj_p;   // p/11
        int tj_k = (k*5958) >> 16;  int mk = k - 11*tj_k;   // k/11
        int ti_k = (k*174763) >> 20; int uk = k - 6*ti_k;   // k/6

        // gather pre-update rows p and k via intra-wave shuffles (source lane: same ti, tj=tj_p/tj_k)
        float tmp[6];
#pragma unroll
        for (int mm = 0; mm < 11; ++mm) if (mm == mp) {
#pragma unroll
            for (int u = 0; u < 6; ++u) tmp[u] = a[mm][u];
        }
        int lsrc_p = (l & 48) | tj_p;
        int lsrc_k = (l & 48) | tj_k;
        float pr[6];
#pragma unroll
        for (int u = 0; u < 6; ++u) pr[u] = __shfl(tmp[u], lsrc_p, 64);
#pragma unroll
        for (int mm = 0; mm < 11; ++mm) if (mm == mk) {
#pragma unroll
            for (int u = 0; u < 6; ++u) tmp[u] = a[mm][u];
        }
        float kr[6];
#pragma unroll
        for (int u = 0; u < 6; ++u) kr[u] = __shfl(tmp[u], lsrc_k, 64);

        // d[m] = col k at my rows (from LDS, published last phase); dk = col k at row k
        float d[11];
#pragma unroll
        for (int m = 0; m < 11; ++m) d[m] = dcolB[par][tj*11 + m];
        float dk = dcolB[par][k];

        // s[u]; col-k specials
        bool myg = (ti == ti_k);
        float s[6];
#pragma unroll
        for (int u = 0; u < 6; ++u) {
            float su = pr[u] * invpv;
            bool isuk = myg && (u == uk);
            s[u] = isuk ? invpv : su;
            kr[u] = isuk ? 0.0f : kr[u];
            if (isuk) {
#pragma unroll
                for (int m = 0; m < 11; ++m) a[m][u] = 0.0f;   // pre-zero col k
            }
        }
        // rank-1 update
#pragma unroll
        for (int m = 0; m < 11; ++m)
#pragma unroll
          for (int u = 0; u < 6; ++u)
            a[m][u] = __builtin_fmaf(-d[m], s[u], a[m][u]);
        // row k overwrite: scaled pivot row
        if (tj == tj_k) {
#pragma unroll
            for (int mm = 0; mm < 11; ++mm) if (mm == mk) {
#pragma unroll
                for (int u = 0; u < 6; ++u) a[mm][u] = s[u];
            }
        }
        // row p overwrite: old row k eliminated
        if (p != k && tj == tj_p) {
#pragma unroll
            for (int mm = 0; mm < 11; ++mm) if (mm == mp) {
#pragma unroll
                for (int u = 0; u < 6; ++u) a[mm][u] = __builtin_fmaf(-dk, s[u], kr[u]);
            }
        }
        if (tid == 0) perm[k] = p;

        // publish col k+1 (updated) + its pivot, owner wave, in-register search
        if (k < PP-1) {
            int kn = k + 1;
            int tin = (kn*174763) >> 20;
            int un  = kn - 6*tin;
            if (ti == tin) {
                float v[11];
#pragma unroll
                for (int uu = 0; uu < 6; ++uu) if (uu == un) {
#pragma unroll
                    for (int m = 0; m < 11; ++m) v[m] = a[m][uu];
                }
#pragma unroll
                for (int m = 0; m < 11; ++m) dcolB[npar][tj*11 + m] = v[m];
                unsigned key = 0; float val = 0.0f;
#pragma unroll
                for (int m = 0; m < 11; ++m) {
                    int r = tj*11 + m;
                    if (r >= kn && r < PP) {
                        unsigned bits = __float_as_uint(fabsf(v[m]));
                        unsigned kk2 = (bits & 0xFFFFFF00u) | (unsigned)(255 - r);
                        if (kk2 > key) { key = kk2; val = v[m]; }
                    }
                }
#pragma unroll
                for (int mm = 1; mm < 16; mm <<= 1) {
                    unsigned ok = __shfl_xor(key, mm);
                    float    ov = __shfl_xor(val, mm);
                    if (ok > key) { key = ok; val = ov; }
                }
                if (tj == 0) { pbuf[npar] = 255 - (int)(key & 0xFFu); pvbuf[npar] = val; }
            }
        }
        __syncthreads();   // the ONE barrier
    }

    // column-unswap via per-thread permutation replay (k = 168..0: swap(col k, col perm[k]))
    int pos[6];
#pragma unroll
    for (int u = 0; u < 6; ++u) pos[u] = ti*6 + u;
    for (int k = PP-1; k >= 0; --k) {
        int pp = perm[k];
#pragma unroll
        for (int u = 0; u < 6; ++u) {
            int po = pos[u];
            pos[u] = (po == k) ? pp : ((po == pp) ? k : po);
        }
    }
    // scattered writeout: Pinv -> prep2 frag layout, split hi/lo (padding pre-zeroed by memset)
#pragma unroll
    for (int u = 0; u < 6; ++u) {
        int c = ti*6 + u;
        if (c < PP) {
            int kk = pos[u];
            int ks = kk >> 5, qq = (kk >> 3) & 3, j = kk & 7;
#pragma unroll
            for (int m = 0; m < 11; ++m) {
                int r = tj*11 + m;
                if (r < PP) {
                    int mt = r >> 4, lr = r & 15;
                    float val = a[m][u];
                    ushort h = f2bf(val);
                    ushort lo = f2bf(val - bf2f(h));
                    int base = ((ks*2+0)*11 + mt)*512 + (qq*16 + lr)*8 + j;
                    prep2[base] = h;
                    prep2[base + 11*512] = lo;
                }
            }
        }
    }
}

// ---------------- fused: 1-wave blocks, 32 cols, no inter-wave coupling ----------------
__device__ __forceinline__ f32x4 mfma3(short8_t ah, short8_t al, short8_t bh, short8_t bl, f32x4 acc) {
    acc = __builtin_amdgcn_mfma_f32_16x16x32_bf16(ah, bh, acc, 0, 0, 0);
    acc = __builtin_amdgcn_mfma_f32_16x16x32_bf16(al, bh, acc, 0, 0, 0);
    acc = __builtin_amdgcn_mfma_f32_16x16x32_bf16(ah, bl, acc, 0, 0, 0);
    return acc;
}

// LDS (12288 B): t-transpose bounce [rp 0..95][c 0..15] uint2 {hi,lo}; fold footprint aliases it.
__global__ __launch_bounds__(64, 3) void fused_kernel(
    const float* __restrict__ x,
    const ushort* __restrict__ prep1,
    const ushort* __restrict__ prep2,
    const float* __restrict__ sigma_,
    float* __restrict__ wmap,
    float* __restrict__ num)
{
    extern __shared__ char smem[];
    uint*  lds_t = (uint*)smem;          // (rp*16+c)*2 dword index, uint2 per slot
    float* fpf   = (float*)smem;         // fold footprint 13x44, aliases lds_t

    int l = threadIdx.x;
    int q = l >> 4, c = l & 15;
    int n = blockIdx.z;
    int ho = blockIdx.y;
    int wo0 = blockIdx.x * 32;
    float lam = 6.0f * sigma_[0];
    const float* xn = x + n*HIMG*HIMG;
    const short8_t* p1v = reinterpret_cast<const short8_t*>(prep1);
    const short8_t* p2v = reinterpret_cast<const short8_t*>(prep2);

    f32x4 acc[11][2];
#pragma unroll
    for (int mt = 0; mt < 11; ++mt)
#pragma unroll
      for (int cf = 0; cf < 2; ++cf) acc[mt][cf] = (f32x4){0.f,0.f,0.f,0.f};

    // ---- GEMM1: build B from x (reflect-pad fused) per ks, stream A1 from L2 ----
#pragma unroll 1
    for (int ks = 0; ks < 6; ++ks) {
        short8_t bh[2], bl[2];
#pragma unroll
        for (int cf = 0; cf < 2; ++cf) {
#pragma unroll
            for (int j = 0; j < 8; ++j) {
                int k = ks*32 + 8*q + j;
                float v = 0.0f;
                if (k < PP) {
                    int di = (k*5042) >> 16;            // k/13
                    int dj = k - 13*di;
                    int gi = ho + di - 12;
                    gi = (gi < 0) ? -gi : gi; gi = (gi > HIMG-1) ? (2*(HIMG-1) - gi) : gi;
                    int gj = wo0 + cf*16 + c + dj - 12;
                    gj = (gj < 0) ? -gj : gj; gj = (gj > HIMG-1) ? (2*(HIMG-1) - gj) : gj;
                    v = 2.0f * xn[gi*HIMG + gj] - 1.0f;
                }
                ushort h = f2bf(v);
                bh[cf][j] = (short)h;
                bl[cf][j] = (short)f2bf(v - bf2f(h));
            }
        }
#pragma unroll
        for (int mt = 0; mt < 11; ++mt) {
            short8_t ah = p1v[((ks*2+0)*11 + mt)*64 + l];
            short8_t al = p1v[((ks*2+1)*11 + mt)*64 + l];
            acc[mt][0] = mfma3(ah, al, bh[0], bl[0], acc[mt][0]);
            acc[mt][1] = mfma3(ah, al, bh[1], bl[1], acc[mt][1]);
        }
    }

    // ---- per cf: threshold+count -> transpose t via LDS -> GEMM2 into same acc ----
    float wgts[2];
#pragma unroll
    for (int cf = 0; cf < 2; ++cf) {
        __syncthreads();   // lds_t free (prev cf's reads done)
        int cadd = 0;
#pragma unroll
        for (int mt = 0; mt < 11; ++mt) {
            uint ph[2], pl[2];
#pragma unroll
            for (int d = 0; d < 2; ++d) {
                ushort th2[2], tl2[2];
#pragma unroll
                for (int e2 = 0; e2 < 2; ++e2) {
                    int e = 2*d + e2;
                    int r = mt*16 + 4*q + e;
                    float dd = acc[mt][cf][e] / lam;
                    bool keep = fabsf(dd) > 1.0f;
                    float tv = keep ? dd*lam : 0.0f;
                    cadd += (keep && r > 0 && r < PP) ? 1 : 0;
                    th2[e2] = f2bf(tv);
                    tl2[e2] = f2bf(tv - bf2f(th2[e2]));
                }
                ph[d] = (uint)th2[0] | ((uint)th2[1] << 16);
                pl[d] = (uint)tl2[0] | ((uint)tl2[1] << 16);
            }
#pragma unroll
            for (int d = 0; d < 2; ++d) {
                int rp = mt*8 + q*2 + d;
                uint2 vv; vv.x = ph[d]; vv.y = pl[d];
                *reinterpret_cast<uint2*>(&lds_t[(rp*16 + c)*2]) = vv;
            }
        }
        // zero padding rows rp 88..95 (rows 176..191)
        {
            int rp = 88 + (l >> 3);
            int cc = (l & 7) * 2;
            uint2 z; z.x = 0u; z.y = 0u;
            *reinterpret_cast<uint2*>(&lds_t[(rp*16 + cc)*2]) = z;
            *reinterpret_cast<uint2*>(&lds_t[(rp*16 + cc + 1)*2]) = z;
        }
        // count -> weight (butterfly over q groups; all lanes get result)
        cadd += __shfl_xor(cadd, 16);
        cadd += __shfl_xor(cadd, 32);
        int wo = wo0 + cf*16 + c;
        float wgt = (wo < HO) ? 1.0f/(1.0f + (float)cadd) : 0.0f;
        wgts[cf] = wgt;
        if (q == 0 && wo < HO) wmap[(n*HO + ho)*HO + wo] = wgt;
        __syncthreads();   // t visible
        // GEMM2 into same acc slots (t for this cf now lives in LDS)
#pragma unroll
        for (int mt = 0; mt < 11; ++mt) acc[mt][cf] = (f32x4){0.f,0.f,0.f,0.f};
#pragma unroll 1
        for (int ks = 0; ks < 6; ++ks) {
            union { short8_t s; uint dd[4]; } BH, BL;
#pragma unroll
            for (int jp = 0; jp < 4; ++jp) {
                uint2 vv = *reinterpret_cast<const uint2*>(&lds_t[((ks*16 + 4*q + jp)*16 + c)*2]);
                BH.dd[jp] = vv.x; BL.dd[jp] = vv.y;
            }
#pragma unroll
            for (int mt = 0; mt < 11; ++mt) {
                short8_t ah = p2v[((ks*2+0)*11 + mt)*64 + l];
                short8_t al = p2v[((ks*2+1)*11 + mt)*64 + l];
                acc[mt][cf] = mfma3(ah, al, BH.s, BL.s, acc[mt][cf]);
            }
        }
    }

    // ---- fold: footprint in LDS (aliases lds_t), then global atomics ----
    __syncthreads();
    for (int idx = l; idx < 572; idx += 64) fpf[idx] = 0.0f;
    __syncthreads();
#pragma unroll
    for (int cf = 0; cf < 2; ++cf) {
#pragma unroll
        for (int mt = 0; mt < 11; ++mt) {
#pragma unroll
            for (int e = 0; e < 4; ++e) {
                int r = mt*16 + 4*q + e;
                if (r < PP) {
                    int di = (r*5042) >> 16;
                    int dj = r - 13*di;
                    atomicAdd(&fpf[di*44 + cf*16 + c + dj], acc[mt][cf][e] * wgts[cf]);
                }
            }
        }
    }
    __syncthreads();
    float* nump = num + n*HP*HP;
    for (int idx = l; idx < 572; idx += 64) {
        int di = (idx*1490) >> 16;                  // idx/44
        int jj = idx - di*44;
        int gj = wo0 + jj;
        if (gj < HP) atomicAdd(&nump[(ho + di)*HP + gj], fpf[idx]);
    }
}

// ---------------- final: out = (num / box13(w) + 1)/2 (verified) ----------------
__global__ __launch_bounds__(256) void final_kernel(const float* __restrict__ num,
                                                    const float* __restrict__ wmap,
                                                    float* __restrict__ out)
{
    __shared__ float wr[28][28];
    int tid = threadIdx.x;
    int n = blockIdx.z;
    int y0 = blockIdx.y * 16, x0 = blockIdx.x * 16;
    const float* wp = wmap + n*HO*HO;
    for (int idx = tid; idx < 28*28; idx += 256) {
        int i = idx / 28, j = idx - (idx/28)*28;
        wr[i][j] = wp[(y0 + i)*HO + (x0 + j)];
    }
    __syncthreads();
    int py = tid >> 4, px = tid & 15;
    float dv = 0.0f;
#pragma unroll
    for (int a = 0; a < 13; ++a)
#pragma unroll
        for (int b = 0; b < 13; ++b)
            dv += wr[py + a][px + b];
    int y = y0 + py, x = x0 + px;
    float nv = num[(n*HP + (y + 12))*HP + (x + 12)];
    out[(n*HIMG + y)*HIMG + x] = (nv / dv + 1.0f) * 0.5f;
}

extern "C" void kernel_launch(void* const* d_in, const int* in_sizes, int n_in,
                              void* d_out, int out_size, void* d_ws, size_t ws_size,
                              hipStream_t stream) {
    const float* x      = (const float*)d_in[0];
    const float* sigma_ = (const float*)d_in[1];
    const float* Pm1    = (const float*)d_in[2];
    float* ws    = (float*)d_ws;
    float* wmap  = ws;                           // 287296 f
    float* num   = ws + 287296;                  // 313600 f
    ushort* prep1 = (ushort*)(ws + 600896);      // 67584 ushorts
    ushort* prep2 = (ushort*)(ws + 634688);      // 67584 ushorts
    float* out   = (float*)d_out;

    const int FUSED_LDS = 12288;

    hipMemsetAsync(num, 0, (size_t)NIMG*HP*HP*sizeof(float), stream);
    hipMemsetAsync(prep2, 0, (size_t)(6*2*11*512)*sizeof(ushort), stream);
    prep1_kernel<<<(6*11*512 + 255)/256, 256, 0, stream>>>(Pm1, prep1);
    invert_kernel<<<1, 512, 0, stream>>>(Pm1, prep2);
    dim3 grid((HO + 31)/32, HO, NIMG);           // 9 x 268 x 4, 64-thread blocks
    fused_kernel<<<grid, 64, FUSED_LDS, stream>>>(x, prep1, prep2, sigma_, wmap, num);
    dim3 gridD(HIMG/16, HIMG/16, NIMG);
    final_kernel<<<gridD, 256, 0, stream>>>(num, wmap, out);
}